// Round 11
// baseline (2359.770 us; speedup 1.0000x reference)
//
#include <hip/hip_runtime.h>
#include <hip/hip_fp16.h>

#define NT    365
#define NGRID 1000
#define NXI   20
#define HID   256
#define GATES 1024
#define MROWS 365000          // NT*NGRID
#define MBLK  5704            // ceil(MROWS/64)
#define MPAD  (MBLK * 64)
#define NCL   63              // clusters (16 pts each, last ragged)
#define CPTS  16
#define HX_TOT ((size_t)NT * NCL * 1024)   // u64 slots, deep buffer (188MB)
#define HX_ZERO ((size_t)NCL * 1024)       // t=0 region: zeros (h_0 = 0)

typedef _Float16 half8 __attribute__((ext_vector_type(8)));
typedef float floatx4 __attribute__((ext_vector_type(4)));
typedef unsigned long long u64;

#define SENT 0xFFFFFFFFFFFFFFFFull   // 4x fp16 -NaN: unreachable (|h|<=1)

// Module-scope globals (d_ws too small). Fully rewritten/reset every launch.
__device__ _Float16 g_gx[(size_t)MPAD * GATES];   // gx, block-local column layout
__device__ _Float16 g_wif[64 * 8 * 512];          // W_ih B-frags (global n-tiles)
__device__ _Float16 g_whf[2 * 32 * 8 * 64 * 8];   // W_hh B-frags, split by rec block
// h exchange, A-FRAGMENT ORDER, plane-split: chunk[(ks)*64 + lane] (+512 for
// the 2nd u64 of the half8). Coalesced polls AND coalesced publishes (each
// wave owns exactly one ks slice). Sentinel protocol; deep t-indexed buffer.
__device__ u64 g_hx[HX_TOT];

__device__ __forceinline__ float fsig(float x) {
  return __fdividef(1.f, 1.f + __expf(-x));
}
__device__ __forceinline__ float ftanh(float x) {
  return 1.f - __fdividef(2.f, __expf(2.f * x) + 1.f);
}

// ---- pack weights into MFMA B-fragment layouts ----------------------------
// B-frag 16x16x32: lane holds B[n=tile*16+(lane&15)][k=ks*32+(lane>>4)*8+j]
__global__ __launch_bounds__(256) void pack_wf_kernel(
    const float* __restrict__ W_ih, const float* __restrict__ W_hh) {
  const int gid = blockIdx.x * 256 + threadIdx.x;   // 0..65535
  const float* src;
  _Float16* dst;
  int n, k0, lane;
  if (gid < 32768) {                 // W_ih -> g_wif, global n-tile layout
    const int tile = gid >> 9;
    const int ks   = (gid >> 6) & 7;
    lane = gid & 63;
    n  = tile * 16 + (lane & 15);
    k0 = ks * 32 + (lane >> 4) * 8;
    src = W_ih + n * HID + k0;
    dst = g_wif + ((size_t)(tile * 8 + ks) * 64 + lane) * 8;
  } else {                           // W_hh -> g_whf, [b][ltile][ks global]
    const int rem = gid - 32768;
    const int b2  = rem >> 14;       // owning rec block (dim half)
    const int lt  = (rem >> 9) & 31; // local tile = tau*8 + sub
    const int ks  = (rem >> 6) & 7;
    lane = rem & 63;
    const int nt = (lt >> 3) * 16 + b2 * 8 + (lt & 7);
    n  = nt * 16 + (lane & 15);
    k0 = ks * 32 + (lane >> 4) * 8;
    src = W_hh + n * HID + k0;
    dst = g_whf + ((size_t)((b2 * 32 + lt) * 8 + ks) * 64 + lane) * 8;
  }
  const float4 a = *(const float4*)(src);
  const float4 b = *(const float4*)(src + 4);
  half8 h;
  h[0] = (_Float16)a.x; h[1] = (_Float16)a.y; h[2] = (_Float16)a.z; h[3] = (_Float16)a.w;
  h[4] = (_Float16)b.x; h[5] = (_Float16)b.y; h[6] = (_Float16)b.z; h[7] = (_Float16)b.w;
  *(half8*)dst = h;
}

// ---- gx = relu(x@W_in.T+b_in) @ W_ih.T + (b_ih+b_hh), fused ---------------
// Output column layout per row: phi(g) = b*512 + tau*128 + (g&127).
// v4 changes (on v3's swapped-operand MFMA + fused init):
//  * DIRECT GLOBAL STORE: each lane packs 4 consecutive gates into one u64
//    and stores straight to g_gx (same phi map the repack used). s_out and
//    ALL 8 per-ng __syncthreads are deleted — the ng loop is barrier-free.
//  * OCCUPANCY 3 blocks/CU: LDS drops 75->43 KB; __launch_bounds__(256,3).
//    Latency-bound kernel (R4: Occ 13%, pipes <16%) gains 1.5x TLP.
//  * bf pipeline 4-deep -> 2-deep (reg headroom for the 170-reg cap),
//    prologue issued between x0 loop and its barrier (in flight across it).
__global__ __launch_bounds__(256, 3) void gx_kernel(
    const float* __restrict__ x, const float* __restrict__ W_in,
    const float* __restrict__ b_in, const float* __restrict__ b_ih,
    const float* __restrict__ b_hh, float* __restrict__ y) {
  {
    const size_t gid = (size_t)blockIdx.x * 256 + threadIdx.x;
    const size_t TT  = (size_t)MBLK * 256;
    for (size_t j = gid; j < HX_TOT; j += TT)
      g_hx[j] = (j < HX_ZERO) ? 0ull : SENT;
    if (gid < MROWS) y[gid] = 0.f;
  }

  __shared__ float s_x[64 * NXI];
  __shared__ float s_bias[GATES];
  __shared__ _Float16 s_x0[64 * 264];

  const int tid  = threadIdx.x;
  const int lane = tid & 63;
  const int w    = tid >> 6;
  const int jg   = lane >> 4;
  const int m0   = blockIdx.x * 64;

  #pragma unroll
  for (int i = 0; i < 5; ++i) {
    const int idx = i * 256 + tid;
    size_t g = (size_t)m0 * NXI + idx;
    const size_t gmax = (size_t)MROWS * NXI - 1;
    if (g > gmax) g = gmax;
    s_x[idx] = x[g];
  }
  #pragma unroll
  for (int i = 0; i < 4; ++i) {      // bias table: one quad read per gate pack
    const int g = i * 256 + tid;
    s_bias[g] = b_ih[g] + b_hh[g];
  }
  float wv[NXI];
  #pragma unroll
  for (int k = 0; k < NXI; ++k) wv[k] = W_in[tid * NXI + k];
  const float bv = b_in[tid];
  __syncthreads();

  for (int r = 0; r < 64; ++r) {
    float acc = bv;
    #pragma unroll
    for (int qq = 0; qq < 5; ++qq) {
      const float4 xa = *(const float4*)&s_x[r * NXI + qq * 4];
      acc += xa.x * wv[qq * 4 + 0] + xa.y * wv[qq * 4 + 1] +
             xa.z * wv[qq * 4 + 2] + xa.w * wv[qq * 4 + 3];
    }
    s_x0[r * 264 + tid] = (_Float16)fmaxf(acc, 0.f);
  }

  // bf prologue (depth 2): issued before the barrier, in flight across it
  half8 bf[2][4];   // [slot = ks&1][ni]; all indices compile-time
  #pragma unroll
  for (int p = 0; p < 2; ++p)
    #pragma unroll
    for (int ni = 0; ni < 4; ++ni)
      bf[p][ni] = *(const half8*)(g_wif +
          ((size_t)((w * 4 + ni) * 8 + p) * 64 + lane) * 8);
  __syncthreads();

  for (int ng = 0; ng < 4; ++ng) {    // 4 groups of 256 gates; BARRIER-FREE
    floatx4 acc[4][4];
    #pragma unroll
    for (int mi = 0; mi < 4; ++mi)
      #pragma unroll
      for (int ni = 0; ni < 4; ++ni) acc[mi][ni] = (floatx4){0.f, 0.f, 0.f, 0.f};

    #pragma unroll
    for (int ks = 0; ks < 8; ++ks) {
      half8 a[4];
      #pragma unroll
      for (int mi = 0; mi < 4; ++mi)
        a[mi] = *(const half8*)&s_x0[(mi * 16 + (lane & 15)) * 264 + ks * 32 + (lane >> 4) * 8];
      // SWAPPED operands: D = [gate][point] (row = gate = jg*4+r,
      // col = point = lane&15). A/B per-lane layouts identical for 16x16x32.
      #pragma unroll
      for (int mi = 0; mi < 4; ++mi)
        #pragma unroll
        for (int ni = 0; ni < 4; ++ni)
          acc[mi][ni] = __builtin_amdgcn_mfma_f32_16x16x32_f16(bf[ks & 1][ni], a[mi], acc[mi][ni], 0, 0, 0);
      // refill slot ks&1: this ng's ks+2, or next ng's prologue (ks-6)
      if (ks + 2 < 8) {
        #pragma unroll
        for (int ni = 0; ni < 4; ++ni)
          bf[ks & 1][ni] = *(const half8*)(g_wif +
              ((size_t)((ng * 16 + w * 4 + ni) * 8 + (ks + 2)) * 64 + lane) * 8);
      } else if (ng + 1 < 4) {
        #pragma unroll
        for (int ni = 0; ni < 4; ++ni)
          bf[ks & 1][ni] = *(const half8*)(g_wif +
              ((size_t)(((ng + 1) * 16 + w * 4 + ni) * 8 + (ks - 6)) * 64 + lane) * 8);
      }
    }

    // epilogue: lane holds 4 consecutive gates (jg*4..+3) of point lane&15
    // per (mi,ni): add bias quad, pack u64, store DIRECT to g_gx.
    #pragma unroll
    for (int ni = 0; ni < 4; ++ni) {
      const int colw = (w * 4 + ni) * 16 + jg * 4;       // gate-in-ng base
      const float4 bs = *(const float4*)&s_bias[ng * 256 + colw];
      const int phi = ((colw >> 7) & 1) * 512 + ng * 128 + (colw & 127);
      #pragma unroll
      for (int mi = 0; mi < 4; ++mi) {
        union { _Float16 h[4]; u64 u; } pk;
        pk.h[0] = (_Float16)(acc[mi][ni][0] + bs.x);
        pk.h[1] = (_Float16)(acc[mi][ni][1] + bs.y);
        pk.h[2] = (_Float16)(acc[mi][ni][2] + bs.z);
        pk.h[3] = (_Float16)(acc[mi][ni][3] + bs.w);
        *(u64*)(g_gx + (size_t)(m0 + mi * 16 + (lane & 15)) * GATES + phi) = pk.u;
      }
    }
  }
}

// ---- recurrent: 63 clusters x 2 blocks; wave-autonomous gate slices -------
// EXACT R7/R9/R10 kernel (best measured: 1254us). gx one-step-ahead
// prefetch issued after spin exit; __syncthreads step barrier.
__global__ __launch_bounds__(256, 1) void rec_kernel(
    const float* __restrict__ W_out, const float* __restrict__ b_out,
    float* __restrict__ y) {
  __shared__ float s_g[4 * 16 * 132];  // per-wave gate regions (pad 132)
  __shared__ u64   s_h[2][1024];       // own-half h, A-order, dbl-buffered

  const int tid = threadIdx.x;
  const int l   = tid & 63;
  const int w   = tid >> 6;
  const int c   = blockIdx.x >> 1;     // cluster
  const int b   = blockIdx.x & 1;      // dim-half owner
  const int pt  = l & 15;
  const int jg  = l >> 4;

  // one-time: W_hh slice -> registers. slot = off*2+s (all reg indices are
  // compile-time constants; runtime w/b only in ADDRESSES).
  half8 wf[8][8];
  #pragma unroll
  for (int slot = 0; slot < 8; ++slot) {
    const int lt = (slot >> 1) * 8 + 2 * w + (slot & 1);
    #pragma unroll
    for (int kk = 0; kk < 4; ++kk) {
      wf[slot][kk] = *(const half8*)(g_whf +
          ((size_t)((b * 32 + lt) * 8 + (b * 4 + kk)) * 64 + l) * 8);
      wf[slot][4 + kk] = *(const half8*)(g_whf +
          ((size_t)((b * 32 + lt) * 8 + ((1 - b) * 4 + kk)) * 64 + l) * 8);
    }
  }

  float cs[8];
  float wo[8];
  #pragma unroll
  for (int j = 0; j < 8; ++j) {
    cs[j] = 0.f;
    wo[j] = W_out[b * 128 + 32 * w + jg * 8 + j];
  }
  const float bo_eff = (b == 0 && w == 0) ? b_out[0] : 0.f;
  const int n_pt  = c * CPTS + pt;
  const int rn_pt = (n_pt < NGRID) ? n_pt : (NGRID - 1);
  const int peer0 = (1 - b) * 4;       // peer's global ks base

  // zero s_h buffer 0 (h_0 = 0)
  for (int i = tid; i < 1024; i += 256) s_h[0][i] = 0ull;

  // seed gxr for t=0 (cold; paid once outside the steady-state loop)
  half8 gxr[4];
  {
    const _Float16* gsrc = g_gx + (size_t)rn_pt * GATES + b * 512 + 32 * w + jg * 8;
    #pragma unroll
    for (int off = 0; off < 4; ++off)
      gxr[off] = *(const half8*)(gsrc + off * 128);
  }
  __syncthreads();

  for (int t = 0; t < NT; ++t) {
    const int cur = t & 1, nxt = cur ^ 1;
    const bool hasnext = (t + 1 < NT);

    // 1) issue peer poll loads FIRST (nothing queues ahead of them)
    const u64* hsrc = g_hx + ((size_t)t * NCL + c) * 1024;
    u64 pv[8];
    #pragma unroll
    for (int kk = 0; kk < 4; ++kk) {
      pv[2 * kk]     = __hip_atomic_load(hsrc +       (peer0 + kk) * 64 + l,
                                         __ATOMIC_RELAXED, __HIP_MEMORY_SCOPE_AGENT);
      pv[2 * kk + 1] = __hip_atomic_load(hsrc + 512 + (peer0 + kk) * 64 + l,
                                         __ATOMIC_RELAXED, __HIP_MEMORY_SCOPE_AGENT);
    }

    floatx4 acc[8];
    #pragma unroll
    for (int i = 0; i < 8; ++i) acc[i] = (floatx4){0.f, 0.f, 0.f, 0.f};

    // 2) own-half MFMAs from LDS while peer loads are in flight
    #pragma unroll
    for (int kk = 0; kk < 4; ++kk) {
      union { u64 u[2]; half8 h; } af;
      af.u[0] = s_h[cur][kk * 64 + l];
      af.u[1] = s_h[cur][512 + kk * 64 + l];
      #pragma unroll
      for (int i = 0; i < 8; ++i)
        acc[i] = __builtin_amdgcn_mfma_f32_16x16x32_f16(af.h, wf[i][kk], acc[i], 0, 0, 0);
    }

    // 3) BATCHED spin: re-issue all pending chunks each iteration (~1 RTT)
    {
      bool pending = false;
      #pragma unroll
      for (int k = 0; k < 8; ++k) pending |= (pv[k] == SENT);
      int tries = 0;
      while (pending && ++tries < (1 << 18)) {
        pending = false;
        #pragma unroll
        for (int kk = 0; kk < 4; ++kk) {
          if (pv[2 * kk] == SENT)
            pv[2 * kk] = __hip_atomic_load(hsrc + (peer0 + kk) * 64 + l,
                                           __ATOMIC_RELAXED, __HIP_MEMORY_SCOPE_AGENT);
          if (pv[2 * kk + 1] == SENT)
            pv[2 * kk + 1] = __hip_atomic_load(hsrc + 512 + (peer0 + kk) * 64 + l,
                                               __ATOMIC_RELAXED, __HIP_MEMORY_SCOPE_AGENT);
        }
        #pragma unroll
        for (int k = 0; k < 8; ++k) pending |= (pv[k] == SENT);
      }
    }

    // 4) gx prefetch for t+1 (issued ONLY after the spin has exited; hides
    //    under peer-MFMA + cell; consumed next step from retired registers)
    __builtin_amdgcn_sched_barrier(0);
    half8 gn[4];
    if (hasnext) {
      const _Float16* gsrc = g_gx + ((size_t)(t + 1) * NGRID + rn_pt) * GATES
                           + b * 512 + 32 * w + jg * 8;
      #pragma unroll
      for (int off = 0; off < 4; ++off)
        gn[off] = *(const half8*)(gsrc + off * 128);
    }

    // 5) peer-half MFMAs
    #pragma unroll
    for (int kk = 0; kk < 4; ++kk) {
      union { u64 u[2]; half8 h; } af;
      af.u[0] = pv[2 * kk];
      af.u[1] = pv[2 * kk + 1];
      #pragma unroll
      for (int i = 0; i < 8; ++i)
        acc[i] = __builtin_amdgcn_mfma_f32_16x16x32_f16(af.h, wf[i][4 + kk], acc[i], 0, 0, 0);
    }

    // 6) scatter acc -> wave-local s_g region (no barrier: same-wave reuse)
    #pragma unroll
    for (int slot = 0; slot < 8; ++slot) {
      const int colw = (slot >> 1) * 32 + (slot & 1) * 16 + pt; // pt = lane&15
      #pragma unroll
      for (int r = 0; r < 4; ++r)
        s_g[w * 2112 + (jg * 4 + r) * 132 + colw] = acc[slot][r];
    }

    // 7) cell update for this lane's 8 dims (wave-local gates; lgkm only)
    {
      const float* gp = &s_g[w * 2112 + pt * 132 + jg * 8];
      union { u64 u[2]; _Float16 h[8]; } pub;
      float yp = 0.f;
      #pragma unroll
      for (int j = 0; j < 8; ++j) {
        const float gi = gp[j]      + (float)gxr[0][j];
        const float gf = gp[32 + j] + (float)gxr[1][j];
        const float gg = gp[64 + j] + (float)gxr[2][j];
        const float go = gp[96 + j] + (float)gxr[3][j];
        const float i_ = fsig(gi);
        const float f_ = fsig(gf);
        const float g_ = ftanh(gg);
        const float o_ = fsig(go);
        cs[j] = f_ * cs[j] + i_ * g_;
        const float h = o_ * ftanh(cs[j]);
        pub.h[j] = (_Float16)h;
        yp += wo[j] * h;
      }
      // 8) publish wave's ks slice (2 coalesced 512B stores) + own-half LDS
      if (hasnext) {
        u64* dst = g_hx + ((size_t)(t + 1) * NCL + c) * 1024 + (b * 4 + w) * 64 + l;
        __hip_atomic_store(dst,       pub.u[0], __ATOMIC_RELAXED, __HIP_MEMORY_SCOPE_AGENT);
        __hip_atomic_store(dst + 512, pub.u[1], __ATOMIC_RELAXED, __HIP_MEMORY_SCOPE_AGENT);
      }
      s_h[nxt][w * 64 + l]       = pub.u[0];
      s_h[nxt][512 + w * 64 + l] = pub.u[1];
      // 9) y: reduce partial over the 4 jg-lanes of this pt, then atomicAdd
      yp += __shfl_xor(yp, 16);
      yp += __shfl_xor(yp, 32);
      if (jg == 0 && n_pt < NGRID)
        atomicAdd(&y[(size_t)t * NGRID + n_pt], yp + bo_eff);
    }

    // 10) rotate gx prefetch into place (register moves; gn retired by the
    //     time the next step's cell reads gxr)
    if (hasnext) {
      #pragma unroll
      for (int off = 0; off < 4; ++off) gxr[off] = gn[off];
    }

    __syncthreads(); // single barrier: s_h(t+1) complete across waves
  }
}

extern "C" void kernel_launch(void* const* d_in, const int* in_sizes, int n_in,
                              void* d_out, int out_size, void* d_ws, size_t ws_size,
                              hipStream_t stream) {
  (void)in_sizes; (void)n_in; (void)out_size; (void)d_ws; (void)ws_size;
  const float* x     = (const float*)d_in[0];
  // d_in[1] = wt_ih (zeros in eval mode, unused)
  const float* W_in  = (const float*)d_in[2];
  const float* b_in  = (const float*)d_in[3];
  const float* W_ih  = (const float*)d_in[4];
  const float* W_hh  = (const float*)d_in[5];
  const float* b_ih  = (const float*)d_in[6];
  const float* b_hh  = (const float*)d_in[7];
  const float* W_out = (const float*)d_in[8];
  const float* b_out = (const float*)d_in[9];
  float* y           = (float*)d_out;

  hipLaunchKernelGGL(pack_wf_kernel, dim3(256), dim3(256), 0, stream, W_ih, W_hh);
  hipLaunchKernelGGL(gx_kernel, dim3(MBLK), dim3(256), 0, stream,
                     x, W_in, b_in, b_ih, b_hh, y);
  hipLaunchKernelGGL(rec_kernel, dim3(NCL * 2), dim3(256), 0, stream, W_out, b_out, y);
}

// Round 12
// 1915.481 us; speedup vs baseline: 1.2319x; 1.2319x over previous
//
#include <hip/hip_runtime.h>
#include <hip/hip_fp16.h>

#define NT    365
#define NGRID 1000
#define NXI   20
#define HID   256
#define GATES 1024
#define MROWS 365000          // NT*NGRID
#define MBLK  5704            // ceil(MROWS/64)
#define MPAD  (MBLK * 64)
#define NCL   63              // clusters (16 pts each, last ragged)
#define CPTS  16
#define HX_TOT ((size_t)NT * NCL * 1024)   // u64 slots, deep buffer (188MB)
#define HX_ZERO ((size_t)NCL * 1024)       // t=0 region: zeros (h_0 = 0)

typedef _Float16 half8 __attribute__((ext_vector_type(8)));
typedef float floatx4 __attribute__((ext_vector_type(4)));
typedef unsigned long long u64;

#define SENT 0xFFFFFFFFFFFFFFFFull   // 4x fp16 -NaN: unreachable (|h|<=1)

// Module-scope globals (d_ws too small). Fully rewritten/reset every launch.
// g_gx: u64-packed, TRANSPOSED within each 64-row block:
//   index = (blk*256 + cpack)*64 + rowin,  cpack = phi/4, rowin = row&63.
// gx's epilogue stores hit 128B-contiguous runs (16 consecutive rows per
// 16 lanes); rec's prefetch reads 2 u64 per half8 (also 128B-coalesced).
__device__ u64 g_gx64[(size_t)MPAD * 256];
__device__ _Float16 g_wif[64 * 8 * 512];          // W_ih B-frags (global n-tiles)
__device__ _Float16 g_whf[2 * 32 * 8 * 64 * 8];   // W_hh B-frags, split by rec block
// h exchange, A-FRAGMENT ORDER, plane-split: chunk[(ks)*64 + lane] (+512 for
// the 2nd u64 of the half8). Coalesced polls AND coalesced publishes (each
// wave owns exactly one ks slice). Sentinel protocol; deep t-indexed buffer.
__device__ u64 g_hx[HX_TOT];

__device__ __forceinline__ float fsig(float x) {
  return __fdividef(1.f, 1.f + __expf(-x));
}
__device__ __forceinline__ float ftanh(float x) {
  return 1.f - __fdividef(2.f, __expf(2.f * x) + 1.f);
}

// ---- pack weights into MFMA B-fragment layouts ----------------------------
// B-frag 16x16x32: lane holds B[n=tile*16+(lane&15)][k=ks*32+(lane>>4)*8+j]
__global__ __launch_bounds__(256) void pack_wf_kernel(
    const float* __restrict__ W_ih, const float* __restrict__ W_hh) {
  const int gid = blockIdx.x * 256 + threadIdx.x;   // 0..65535
  const float* src;
  _Float16* dst;
  int n, k0, lane;
  if (gid < 32768) {                 // W_ih -> g_wif, global n-tile layout
    const int tile = gid >> 9;
    const int ks   = (gid >> 6) & 7;
    lane = gid & 63;
    n  = tile * 16 + (lane & 15);
    k0 = ks * 32 + (lane >> 4) * 8;
    src = W_ih + n * HID + k0;
    dst = g_wif + ((size_t)(tile * 8 + ks) * 64 + lane) * 8;
  } else {                           // W_hh -> g_whf, [b][ltile][ks global]
    const int rem = gid - 32768;
    const int b2  = rem >> 14;       // owning rec block (dim half)
    const int lt  = (rem >> 9) & 31; // local tile = tau*8 + sub
    const int ks  = (rem >> 6) & 7;
    lane = rem & 63;
    const int nt = (lt >> 3) * 16 + b2 * 8 + (lt & 7);
    n  = nt * 16 + (lane & 15);
    k0 = ks * 32 + (lane >> 4) * 8;
    src = W_hh + n * HID + k0;
    dst = g_whf + ((size_t)((b2 * 32 + lt) * 8 + ks) * 64 + lane) * 8;
  }
  const float4 a = *(const float4*)(src);
  const float4 b = *(const float4*)(src + 4);
  half8 h;
  h[0] = (_Float16)a.x; h[1] = (_Float16)a.y; h[2] = (_Float16)a.z; h[3] = (_Float16)a.w;
  h[4] = (_Float16)b.x; h[5] = (_Float16)b.y; h[6] = (_Float16)b.z; h[7] = (_Float16)b.w;
  *(half8*)dst = h;
}

// ---- gx = relu(x@W_in.T+b_in) @ W_ih.T + (b_ih+b_hh), fused ---------------
// v5 (fix of v4's store scatter): swapped-operand MFMA + DIRECT u64 store
// into the TRANSPOSED g_gx64 layout -> 128B-contiguous runs (16 rows x 8B
// per 16 lanes). s_out and all 8 per-ng barriers remain deleted; LDS 43KB
// -> __launch_bounds__(256,3); bf pipeline depth 2; fused init preamble.
__global__ __launch_bounds__(256, 3) void gx_kernel(
    const float* __restrict__ x, const float* __restrict__ W_in,
    const float* __restrict__ b_in, const float* __restrict__ b_ih,
    const float* __restrict__ b_hh, float* __restrict__ y) {
  {
    const size_t gid = (size_t)blockIdx.x * 256 + threadIdx.x;
    const size_t TT  = (size_t)MBLK * 256;
    for (size_t j = gid; j < HX_TOT; j += TT)
      g_hx[j] = (j < HX_ZERO) ? 0ull : SENT;
    if (gid < MROWS) y[gid] = 0.f;
  }

  __shared__ float s_x[64 * NXI];
  __shared__ float s_bias[GATES];
  __shared__ _Float16 s_x0[64 * 264];

  const int tid  = threadIdx.x;
  const int lane = tid & 63;
  const int w    = tid >> 6;
  const int jg   = lane >> 4;
  const int m0   = blockIdx.x * 64;

  #pragma unroll
  for (int i = 0; i < 5; ++i) {
    const int idx = i * 256 + tid;
    size_t g = (size_t)m0 * NXI + idx;
    const size_t gmax = (size_t)MROWS * NXI - 1;
    if (g > gmax) g = gmax;
    s_x[idx] = x[g];
  }
  #pragma unroll
  for (int i = 0; i < 4; ++i) {      // bias table: one quad read per gate pack
    const int g = i * 256 + tid;
    s_bias[g] = b_ih[g] + b_hh[g];
  }
  float wv[NXI];
  #pragma unroll
  for (int k = 0; k < NXI; ++k) wv[k] = W_in[tid * NXI + k];
  const float bv = b_in[tid];
  __syncthreads();

  for (int r = 0; r < 64; ++r) {
    float acc = bv;
    #pragma unroll
    for (int qq = 0; qq < 5; ++qq) {
      const float4 xa = *(const float4*)&s_x[r * NXI + qq * 4];
      acc += xa.x * wv[qq * 4 + 0] + xa.y * wv[qq * 4 + 1] +
             xa.z * wv[qq * 4 + 2] + xa.w * wv[qq * 4 + 3];
    }
    s_x0[r * 264 + tid] = (_Float16)fmaxf(acc, 0.f);
  }

  // bf prologue (depth 2): issued before the barrier, in flight across it
  half8 bf[2][4];   // [slot = ks&1][ni]; all indices compile-time
  #pragma unroll
  for (int p = 0; p < 2; ++p)
    #pragma unroll
    for (int ni = 0; ni < 4; ++ni)
      bf[p][ni] = *(const half8*)(g_wif +
          ((size_t)((w * 4 + ni) * 8 + p) * 64 + lane) * 8);
  __syncthreads();

  for (int ng = 0; ng < 4; ++ng) {    // 4 groups of 256 gates; BARRIER-FREE
    floatx4 acc[4][4];
    #pragma unroll
    for (int mi = 0; mi < 4; ++mi)
      #pragma unroll
      for (int ni = 0; ni < 4; ++ni) acc[mi][ni] = (floatx4){0.f, 0.f, 0.f, 0.f};

    #pragma unroll
    for (int ks = 0; ks < 8; ++ks) {
      half8 a[4];
      #pragma unroll
      for (int mi = 0; mi < 4; ++mi)
        a[mi] = *(const half8*)&s_x0[(mi * 16 + (lane & 15)) * 264 + ks * 32 + (lane >> 4) * 8];
      // SWAPPED operands: D = [gate][point] (row = gate = jg*4+r,
      // col = point = lane&15). A/B per-lane layouts identical for 16x16x32.
      #pragma unroll
      for (int mi = 0; mi < 4; ++mi)
        #pragma unroll
        for (int ni = 0; ni < 4; ++ni)
          acc[mi][ni] = __builtin_amdgcn_mfma_f32_16x16x32_f16(bf[ks & 1][ni], a[mi], acc[mi][ni], 0, 0, 0);
      // refill slot ks&1: this ng's ks+2, or next ng's prologue (ks-6)
      if (ks + 2 < 8) {
        #pragma unroll
        for (int ni = 0; ni < 4; ++ni)
          bf[ks & 1][ni] = *(const half8*)(g_wif +
              ((size_t)((ng * 16 + w * 4 + ni) * 8 + (ks + 2)) * 64 + lane) * 8);
      } else if (ng + 1 < 4) {
        #pragma unroll
        for (int ni = 0; ni < 4; ++ni)
          bf[ks & 1][ni] = *(const half8*)(g_wif +
              ((size_t)(((ng + 1) * 16 + w * 4 + ni) * 8 + (ks - 6)) * 64 + lane) * 8);
      }
    }

    // epilogue: lane holds gates colw..colw+3 of point lane&15 per (mi,ni).
    // Store u64 into transposed layout: 16 lanes (pt) -> 16 consecutive
    // u64 = 128B contiguous run; 4 runs (jg) per instruction.
    #pragma unroll
    for (int ni = 0; ni < 4; ++ni) {
      const int colw = (w * 4 + ni) * 16 + jg * 4;       // gate base (mult of 4)
      const float4 bs = *(const float4*)&s_bias[ng * 256 + colw];
      const int phi = ((colw >> 7) & 1) * 512 + ng * 128 + (colw & 127);
      const size_t base = ((size_t)blockIdx.x * 256 + (phi >> 2)) * 64;
      #pragma unroll
      for (int mi = 0; mi < 4; ++mi) {
        union { _Float16 h[4]; u64 u; } pk;
        pk.h[0] = (_Float16)(acc[mi][ni][0] + bs.x);
        pk.h[1] = (_Float16)(acc[mi][ni][1] + bs.y);
        pk.h[2] = (_Float16)(acc[mi][ni][2] + bs.z);
        pk.h[3] = (_Float16)(acc[mi][ni][3] + bs.w);
        g_gx64[base + mi * 16 + (lane & 15)] = pk.u;
      }
    }
  }
}

// ---- recurrent: 63 clusters x 2 blocks; wave-autonomous gate slices -------
// EXACT R7/R10 kernel (best measured: 1254us) except the gxr/gn PREFETCH
// ADDRESS MATH adapted to the transposed g_gx64 layout: 2 u64 loads per
// half8 (16 lanes x 8B contiguous = 128B runs — better coalesced than the
// old 16-row-scattered 16B loads). Prefetch stays off the critical path.
__global__ __launch_bounds__(256, 1) void rec_kernel(
    const float* __restrict__ W_out, const float* __restrict__ b_out,
    float* __restrict__ y) {
  __shared__ float s_g[4 * 16 * 132];  // per-wave gate regions (pad 132)
  __shared__ u64   s_h[2][1024];       // own-half h, A-order, dbl-buffered

  const int tid = threadIdx.x;
  const int l   = tid & 63;
  const int w   = tid >> 6;
  const int c   = blockIdx.x >> 1;     // cluster
  const int b   = blockIdx.x & 1;      // dim-half owner
  const int pt  = l & 15;
  const int jg  = l >> 4;

  // one-time: W_hh slice -> registers. slot = off*2+s (all reg indices are
  // compile-time constants; runtime w/b only in ADDRESSES).
  half8 wf[8][8];
  #pragma unroll
  for (int slot = 0; slot < 8; ++slot) {
    const int lt = (slot >> 1) * 8 + 2 * w + (slot & 1);
    #pragma unroll
    for (int kk = 0; kk < 4; ++kk) {
      wf[slot][kk] = *(const half8*)(g_whf +
          ((size_t)((b * 32 + lt) * 8 + (b * 4 + kk)) * 64 + l) * 8);
      wf[slot][4 + kk] = *(const half8*)(g_whf +
          ((size_t)((b * 32 + lt) * 8 + ((1 - b) * 4 + kk)) * 64 + l) * 8);
    }
  }

  float cs[8];
  float wo[8];
  #pragma unroll
  for (int j = 0; j < 8; ++j) {
    cs[j] = 0.f;
    wo[j] = W_out[b * 128 + 32 * w + jg * 8 + j];
  }
  const float bo_eff = (b == 0 && w == 0) ? b_out[0] : 0.f;
  const int n_pt  = c * CPTS + pt;
  const int rn_pt = (n_pt < NGRID) ? n_pt : (NGRID - 1);
  const int peer0 = (1 - b) * 4;       // peer's global ks base
  const int pc0   = b * 512 + 32 * w + jg * 8;   // physical gate col base

  // zero s_h buffer 0 (h_0 = 0)
  for (int i = tid; i < 1024; i += 256) s_h[0][i] = 0ull;

  // seed gxr for t=0 (cold; paid once outside the steady-state loop)
  half8 gxr[4];
  {
    const size_t grow = (size_t)rn_pt;
    const size_t gbase = (grow >> 6) * 256;
    const size_t rowin = grow & 63;
    #pragma unroll
    for (int off = 0; off < 4; ++off) {
      const size_t i0 = (gbase + ((pc0 + off * 128) >> 2)) * 64 + rowin;
      union { u64 u[2]; half8 h; } gg;
      gg.u[0] = g_gx64[i0];
      gg.u[1] = g_gx64[i0 + 64];
      gxr[off] = gg.h;
    }
  }
  __syncthreads();

  for (int t = 0; t < NT; ++t) {
    const int cur = t & 1, nxt = cur ^ 1;
    const bool hasnext = (t + 1 < NT);

    // 1) issue peer poll loads FIRST (nothing queues ahead of them)
    const u64* hsrc = g_hx + ((size_t)t * NCL + c) * 1024;
    u64 pv[8];
    #pragma unroll
    for (int kk = 0; kk < 4; ++kk) {
      pv[2 * kk]     = __hip_atomic_load(hsrc +       (peer0 + kk) * 64 + l,
                                         __ATOMIC_RELAXED, __HIP_MEMORY_SCOPE_AGENT);
      pv[2 * kk + 1] = __hip_atomic_load(hsrc + 512 + (peer0 + kk) * 64 + l,
                                         __ATOMIC_RELAXED, __HIP_MEMORY_SCOPE_AGENT);
    }

    floatx4 acc[8];
    #pragma unroll
    for (int i = 0; i < 8; ++i) acc[i] = (floatx4){0.f, 0.f, 0.f, 0.f};

    // 2) own-half MFMAs from LDS while peer loads are in flight
    #pragma unroll
    for (int kk = 0; kk < 4; ++kk) {
      union { u64 u[2]; half8 h; } af;
      af.u[0] = s_h[cur][kk * 64 + l];
      af.u[1] = s_h[cur][512 + kk * 64 + l];
      #pragma unroll
      for (int i = 0; i < 8; ++i)
        acc[i] = __builtin_amdgcn_mfma_f32_16x16x32_f16(af.h, wf[i][kk], acc[i], 0, 0, 0);
    }

    // 3) BATCHED spin: re-issue all pending chunks each iteration (~1 RTT)
    {
      bool pending = false;
      #pragma unroll
      for (int k = 0; k < 8; ++k) pending |= (pv[k] == SENT);
      int tries = 0;
      while (pending && ++tries < (1 << 18)) {
        pending = false;
        #pragma unroll
        for (int kk = 0; kk < 4; ++kk) {
          if (pv[2 * kk] == SENT)
            pv[2 * kk] = __hip_atomic_load(hsrc + (peer0 + kk) * 64 + l,
                                           __ATOMIC_RELAXED, __HIP_MEMORY_SCOPE_AGENT);
          if (pv[2 * kk + 1] == SENT)
            pv[2 * kk + 1] = __hip_atomic_load(hsrc + 512 + (peer0 + kk) * 64 + l,
                                               __ATOMIC_RELAXED, __HIP_MEMORY_SCOPE_AGENT);
        }
        #pragma unroll
        for (int k = 0; k < 8; ++k) pending |= (pv[k] == SENT);
      }
    }

    // 4) gx prefetch for t+1 (issued ONLY after the spin has exited; hides
    //    under peer-MFMA + cell; consumed next step from retired registers)
    __builtin_amdgcn_sched_barrier(0);
    u64 gn[8];
    if (hasnext) {
      const size_t grow = (size_t)(t + 1) * NGRID + rn_pt;
      const size_t gbase = (grow >> 6) * 256;
      const size_t rowin = grow & 63;
      #pragma unroll
      for (int off = 0; off < 4; ++off) {
        const size_t i0 = (gbase + ((pc0 + off * 128) >> 2)) * 64 + rowin;
        gn[2 * off]     = g_gx64[i0];
        gn[2 * off + 1] = g_gx64[i0 + 64];
      }
    }

    // 5) peer-half MFMAs
    #pragma unroll
    for (int kk = 0; kk < 4; ++kk) {
      union { u64 u[2]; half8 h; } af;
      af.u[0] = pv[2 * kk];
      af.u[1] = pv[2 * kk + 1];
      #pragma unroll
      for (int i = 0; i < 8; ++i)
        acc[i] = __builtin_amdgcn_mfma_f32_16x16x32_f16(af.h, wf[i][4 + kk], acc[i], 0, 0, 0);
    }

    // 6) scatter acc -> wave-local s_g region (no barrier: same-wave reuse)
    #pragma unroll
    for (int slot = 0; slot < 8; ++slot) {
      const int colw = (slot >> 1) * 32 + (slot & 1) * 16 + pt; // pt = lane&15
      #pragma unroll
      for (int r = 0; r < 4; ++r)
        s_g[w * 2112 + (jg * 4 + r) * 132 + colw] = acc[slot][r];
    }

    // 7) cell update for this lane's 8 dims (wave-local gates; lgkm only)
    {
      const float* gp = &s_g[w * 2112 + pt * 132 + jg * 8];
      union { u64 u[2]; _Float16 h[8]; } pub;
      float yp = 0.f;
      #pragma unroll
      for (int j = 0; j < 8; ++j) {
        const float gi = gp[j]      + (float)gxr[0][j];
        const float gf = gp[32 + j] + (float)gxr[1][j];
        const float gg = gp[64 + j] + (float)gxr[2][j];
        const float go = gp[96 + j] + (float)gxr[3][j];
        const float i_ = fsig(gi);
        const float f_ = fsig(gf);
        const float g_ = ftanh(gg);
        const float o_ = fsig(go);
        cs[j] = f_ * cs[j] + i_ * g_;
        const float h = o_ * ftanh(cs[j]);
        pub.h[j] = (_Float16)h;
        yp += wo[j] * h;
      }
      // 8) publish wave's ks slice (2 coalesced 512B stores) + own-half LDS
      if (hasnext) {
        u64* dst = g_hx + ((size_t)(t + 1) * NCL + c) * 1024 + (b * 4 + w) * 64 + l;
        __hip_atomic_store(dst,       pub.u[0], __ATOMIC_RELAXED, __HIP_MEMORY_SCOPE_AGENT);
        __hip_atomic_store(dst + 512, pub.u[1], __ATOMIC_RELAXED, __HIP_MEMORY_SCOPE_AGENT);
      }
      s_h[nxt][w * 64 + l]       = pub.u[0];
      s_h[nxt][512 + w * 64 + l] = pub.u[1];
      // 9) y: reduce partial over the 4 jg-lanes of this pt, then atomicAdd
      yp += __shfl_xor(yp, 16);
      yp += __shfl_xor(yp, 32);
      if (jg == 0 && n_pt < NGRID)
        atomicAdd(&y[(size_t)t * NGRID + n_pt], yp + bo_eff);
    }

    // 10) rotate gx prefetch into place (register moves; gn retired by the
    //     time the next step's cell reads gxr)
    if (hasnext) {
      #pragma unroll
      for (int off = 0; off < 4; ++off) {
        union { u64 u[2]; half8 h; } gg;
        gg.u[0] = gn[2 * off];
        gg.u[1] = gn[2 * off + 1];
        gxr[off] = gg.h;
      }
    }

    __syncthreads(); // single barrier: s_h(t+1) complete across waves
  }
}

extern "C" void kernel_launch(void* const* d_in, const int* in_sizes, int n_in,
                              void* d_out, int out_size, void* d_ws, size_t ws_size,
                              hipStream_t stream) {
  (void)in_sizes; (void)n_in; (void)out_size; (void)d_ws; (void)ws_size;
  const float* x     = (const float*)d_in[0];
  // d_in[1] = wt_ih (zeros in eval mode, unused)
  const float* W_in  = (const float*)d_in[2];
  const float* b_in  = (const float*)d_in[3];
  const float* W_ih  = (const float*)d_in[4];
  const float* W_hh  = (const float*)d_in[5];
  const float* b_ih  = (const float*)d_in[6];
  const float* b_hh  = (const float*)d_in[7];
  const float* W_out = (const float*)d_in[8];
  const float* b_out = (const float*)d_in[9];
  float* y           = (float*)d_out;

  hipLaunchKernelGGL(pack_wf_kernel, dim3(256), dim3(256), 0, stream, W_ih, W_hh);
  hipLaunchKernelGGL(gx_kernel, dim3(MBLK), dim3(256), 0, stream,
                     x, W_in, b_in, b_ih, b_hh, y);
  hipLaunchKernelGGL(rec_kernel, dim3(NCL * 2), dim3(256), 0, stream, W_out, b_out, y);
}

// Round 13
// 1633.777 us; speedup vs baseline: 1.4444x; 1.1724x over previous
//
#include <hip/hip_runtime.h>
#include <hip/hip_fp16.h>

#define NT    365
#define NGRID 1000
#define NXI   20
#define HID   256
#define GATES 1024
#define MROWS 365000          // NT*NGRID
#define MBLK  5704            // ceil(MROWS/64)
#define MPAD  (MBLK * 64)
#define NCL   63              // clusters (16 pts each, last ragged)
#define CPTS  16
#define HX_TOT ((size_t)NT * NCL * 1024)   // u64 slots, deep buffer (188MB)
#define HX_ZERO ((size_t)NCL * 1024)       // t=0 region: zeros (h_0 = 0)

typedef _Float16 half8 __attribute__((ext_vector_type(8)));
typedef float floatx4 __attribute__((ext_vector_type(4)));
typedef unsigned long long u64;

#define SENT 0xFFFFFFFFFFFFFFFFull   // 4x fp16 -NaN: unreachable (|h|<=1)

// Module-scope globals (d_ws too small). Fully rewritten/reset every launch.
// g_gx: R10 row-major layout (load-bearing for L3 absorption — R12 showed
// transposing it costs +323MB HBM fetch in rec).
__device__ _Float16 g_gx[(size_t)MPAD * GATES];   // gx, block-local column layout
__device__ _Float16 g_wif[64 * 8 * 512];          // W_ih B-frags (global n-tiles)
// W_hh frags in the DELTA k-order (see rec): position (jg,j) holds dim
// ks*32 + ((j<4) ? jg*4+j : 16+jg*4+(j-4)). Any consistent k-permutation is
// GEMM-valid; this one makes rec's swapped-operand cell fully lane-local.
__device__ _Float16 g_whf[2 * 32 * 8 * 64 * 8];
// h exchange, A/B-FRAGMENT ORDER (delta k-order), plane-split:
// chunk[(ks)*64 + lane] (+512 for the 2nd u64). Sentinel protocol; deep
// t-indexed buffer.
__device__ u64 g_hx[HX_TOT];

__device__ __forceinline__ float fsig(float x) {
  return __fdividef(1.f, 1.f + __expf(-x));
}
__device__ __forceinline__ float ftanh(float x) {
  return 1.f - __fdividef(2.f, __expf(2.f * x) + 1.f);
}

// ---- pack weights into MFMA fragment layouts ------------------------------
// g_wif (B-frag for gx): lane holds B[n][k contiguous] — unchanged.
// g_whf (A-frag for rec): DELTA k-order: float4 a from k0, float4 b from
// k0+16, with k0 = ks*32 + (lane>>4)*4.
__global__ __launch_bounds__(256) void pack_wf_kernel(
    const float* __restrict__ W_ih, const float* __restrict__ W_hh) {
  const int gid = blockIdx.x * 256 + threadIdx.x;   // 0..65535
  const float* srcA;
  const float* srcB;
  _Float16* dst;
  if (gid < 32768) {                 // W_ih -> g_wif, global n-tile layout
    const int tile = gid >> 9;
    const int ks   = (gid >> 6) & 7;
    const int lane = gid & 63;
    const int n  = tile * 16 + (lane & 15);
    const int k0 = ks * 32 + (lane >> 4) * 8;
    srcA = W_ih + n * HID + k0;
    srcB = srcA + 4;
    dst = g_wif + ((size_t)(tile * 8 + ks) * 64 + lane) * 8;
  } else {                           // W_hh -> g_whf, [b][ltile][ks], delta-k
    const int rem = gid - 32768;
    const int b2  = rem >> 14;       // owning rec block (dim half)
    const int lt  = (rem >> 9) & 31; // local tile = off*8 + 2w + s
    const int ks  = (rem >> 6) & 7;
    const int lane = rem & 63;
    const int nt = (lt >> 3) * 16 + b2 * 8 + (lt & 7);
    const int n  = nt * 16 + (lane & 15);
    const int k0 = ks * 32 + (lane >> 4) * 4;        // DELTA order
    srcA = W_hh + n * HID + k0;
    srcB = W_hh + n * HID + k0 + 16;
    dst = g_whf + ((size_t)((b2 * 32 + lt) * 8 + ks) * 64 + lane) * 8;
  }
  const float4 a = *(const float4*)(srcA);
  const float4 b = *(const float4*)(srcB);
  half8 h;
  h[0] = (_Float16)a.x; h[1] = (_Float16)a.y; h[2] = (_Float16)a.z; h[3] = (_Float16)a.w;
  h[4] = (_Float16)b.x; h[5] = (_Float16)b.y; h[6] = (_Float16)b.z; h[7] = (_Float16)b.w;
  *(half8*)dst = h;
}

// ---- gx = relu(x@W_in.T+b_in) @ W_ih.T + (b_ih+b_hh), fused ---------------
// EXACT R10 gx (best measured): fused init preamble, swapped-operand MFMA,
// s_bias quad + u64 pack into s_out, coalesced repack to g_gx, 4-deep bf
// register pipeline, __launch_bounds__(256,2).
__global__ __launch_bounds__(256, 2) void gx_kernel(
    const float* __restrict__ x, const float* __restrict__ W_in,
    const float* __restrict__ b_in, const float* __restrict__ b_ih,
    const float* __restrict__ b_hh, float* __restrict__ y) {
  {
    const size_t gid = (size_t)blockIdx.x * 256 + threadIdx.x;
    const size_t TT  = (size_t)MBLK * 256;
    for (size_t j = gid; j < HX_TOT; j += TT)
      g_hx[j] = (j < HX_ZERO) ? 0ull : SENT;
    if (gid < MROWS) y[gid] = 0.f;
  }

  __shared__ float s_x[64 * NXI];
  __shared__ float s_bias[GATES];
  __shared__ _Float16 s_x0[64 * 264];
  __shared__ _Float16 s_out[64 * 264];

  const int tid  = threadIdx.x;
  const int lane = tid & 63;
  const int w    = tid >> 6;
  const int jg   = lane >> 4;
  const int m0   = blockIdx.x * 64;

  #pragma unroll
  for (int i = 0; i < 5; ++i) {
    const int idx = i * 256 + tid;
    size_t g = (size_t)m0 * NXI + idx;
    const size_t gmax = (size_t)MROWS * NXI - 1;
    if (g > gmax) g = gmax;
    s_x[idx] = x[g];
  }
  #pragma unroll
  for (int i = 0; i < 4; ++i) {      // bias table: one quad read per gate pack
    const int g = i * 256 + tid;
    s_bias[g] = b_ih[g] + b_hh[g];
  }
  float wv[NXI];
  #pragma unroll
  for (int k = 0; k < NXI; ++k) wv[k] = W_in[tid * NXI + k];
  const float bv = b_in[tid];
  __syncthreads();

  // ---- prologue: ng=0, ks=0..3 B-frags in flight across the x0 loop ------
  half8 bf[4][4];   // [slot = ks&3][ni]; all indices compile-time
  #pragma unroll
  for (int p = 0; p < 4; ++p)
    #pragma unroll
    for (int ni = 0; ni < 4; ++ni)
      bf[p][ni] = *(const half8*)(g_wif +
          ((size_t)((w * 4 + ni) * 8 + p) * 64 + lane) * 8);

  for (int r = 0; r < 64; ++r) {
    float acc = bv;
    #pragma unroll
    for (int qq = 0; qq < 5; ++qq) {
      const float4 xa = *(const float4*)&s_x[r * NXI + qq * 4];
      acc += xa.x * wv[qq * 4 + 0] + xa.y * wv[qq * 4 + 1] +
             xa.z * wv[qq * 4 + 2] + xa.w * wv[qq * 4 + 3];
    }
    s_x0[r * 264 + tid] = (_Float16)fmaxf(acc, 0.f);
  }
  __syncthreads();

  for (int ng = 0; ng < 4; ++ng) {    // 4 groups of 256 gates
    floatx4 acc[4][4];
    #pragma unroll
    for (int mi = 0; mi < 4; ++mi)
      #pragma unroll
      for (int ni = 0; ni < 4; ++ni) acc[mi][ni] = (floatx4){0.f, 0.f, 0.f, 0.f};

    #pragma unroll
    for (int ks = 0; ks < 8; ++ks) {
      half8 a[4];
      #pragma unroll
      for (int mi = 0; mi < 4; ++mi)
        a[mi] = *(const half8*)&s_x0[(mi * 16 + (lane & 15)) * 264 + ks * 32 + (lane >> 4) * 8];
      // SWAPPED operands: D = [gate][point] (row = gate = jg*4+r,
      // col = point = lane&15).
      #pragma unroll
      for (int mi = 0; mi < 4; ++mi)
        #pragma unroll
        for (int ni = 0; ni < 4; ++ni)
          acc[mi][ni] = __builtin_amdgcn_mfma_f32_16x16x32_f16(bf[ks & 3][ni], a[mi], acc[mi][ni], 0, 0, 0);
      // refill slot ks&3: this ng's ks+4, or next ng's prologue (ks-4)
      if (ks + 4 < 8) {
        #pragma unroll
        for (int ni = 0; ni < 4; ++ni)
          bf[ks & 3][ni] = *(const half8*)(g_wif +
              ((size_t)((ng * 16 + w * 4 + ni) * 8 + (ks + 4)) * 64 + lane) * 8);
      } else if (ng + 1 < 4) {
        #pragma unroll
        for (int ni = 0; ni < 4; ++ni)
          bf[ks & 3][ni] = *(const half8*)(g_wif +
              ((size_t)(((ng + 1) * 16 + w * 4 + ni) * 8 + (ks - 4)) * 64 + lane) * 8);
      }
    }

    // epilogue: lane holds 4 consecutive gates (jg*4..+3) of point lane&15
    // per (mi,ni): bias quad = 1 ds_read_b128; packed store = 1 ds_write_b64.
    #pragma unroll
    for (int ni = 0; ni < 4; ++ni) {
      const int gbase = ng * 256 + (w * 4 + ni) * 16 + jg * 4;
      const float4 bs = *(const float4*)&s_bias[gbase];
      const int colw = (w * 4 + ni) * 16 + jg * 4;
      #pragma unroll
      for (int mi = 0; mi < 4; ++mi) {
        union { _Float16 h[4]; u64 u; } pk;
        pk.h[0] = (_Float16)(acc[mi][ni][0] + bs.x);
        pk.h[1] = (_Float16)(acc[mi][ni][1] + bs.y);
        pk.h[2] = (_Float16)(acc[mi][ni][2] + bs.z);
        pk.h[3] = (_Float16)(acc[mi][ni][3] + bs.w);
        *(u64*)&s_out[(mi * 16 + (lane & 15)) * 264 + colw] = pk.u;
      }
    }
    __syncthreads();

    #pragma unroll
    for (int i = 0; i < 8; ++i) {
      const int cid = i * 256 + tid;             // 2048 chunks of 8 halfs
      const int row = cid >> 5;
      const int c8  = (cid & 31) * 8;
      const half8 v = *(const half8*)&s_out[row * 264 + c8];
      const int phi = ((c8 >> 7) & 1) * 512 + ng * 128 + (c8 & 127);
      *(half8*)(g_gx + (size_t)(m0 + row) * GATES + phi) = v;
    }
    __syncthreads();
  }
}

// ---- recurrent: 63 clusters x 2 blocks; REGISTER-LOCAL CELL ---------------
// R7/R10 base + SWAPPED-OPERAND MFMA: mfma(wf, h) gives D[dim][point], so
// lane (pt=l&15, jg=l>>4) directly holds, per gate, dims
// {s*16 + jg*4 + r} of point pt. The s_g LDS round-trip (32 ds_write +
// 8 ds_read_b128 + lgkm waits per step, on the serial chain) is DELETED —
// cell update is 100% register-resident. The non-contiguous dim set is
// absorbed by the DELTA k-order of the h exchange (pack_wf packs W_hh's k
// accordingly; gxr and W_out use matching addresses; publish format is
// unchanged since the lane's natural value order IS delta).
__global__ __launch_bounds__(256, 1) void rec_kernel(
    const float* __restrict__ W_out, const float* __restrict__ b_out,
    float* __restrict__ y) {
  __shared__ u64 s_h[2][1024];       // own-half h, delta-order, dbl-buffered

  const int tid = threadIdx.x;
  const int l   = tid & 63;
  const int w   = tid >> 6;
  const int c   = blockIdx.x >> 1;     // cluster
  const int b   = blockIdx.x & 1;      // dim-half owner
  const int pt  = l & 15;
  const int jg  = l >> 4;

  // one-time: W_hh slice -> registers (delta k-order via pack_wf).
  half8 wf[8][8];
  #pragma unroll
  for (int slot = 0; slot < 8; ++slot) {
    const int lt = (slot >> 1) * 8 + 2 * w + (slot & 1);
    #pragma unroll
    for (int kk = 0; kk < 4; ++kk) {
      wf[slot][kk] = *(const half8*)(g_whf +
          ((size_t)((b * 32 + lt) * 8 + (b * 4 + kk)) * 64 + l) * 8);
      wf[slot][4 + kk] = *(const half8*)(g_whf +
          ((size_t)((b * 32 + lt) * 8 + ((1 - b) * 4 + kk)) * 64 + l) * 8);
    }
  }

  // lane's 8 dims (delta order): j<4 -> 32w+jg*4+j ; j>=4 -> 32w+16+jg*4+(j-4)
  float cs[8];
  float wo[8];
  #pragma unroll
  for (int j = 0; j < 8; ++j) {
    const int d = (j < 4) ? (jg * 4 + j) : (16 + jg * 4 + (j - 4));
    cs[j] = 0.f;
    wo[j] = W_out[b * 128 + 32 * w + d];
  }
  const float bo_eff = (b == 0 && w == 0) ? b_out[0] : 0.f;
  const int n_pt  = c * CPTS + pt;
  const int rn_pt = (n_pt < NGRID) ? n_pt : (NGRID - 1);
  const int peer0 = (1 - b) * 4;       // peer's global ks base
  const int gc0   = b * 512 + 32 * w + jg * 4;   // gx col base (delta)

  // zero s_h buffer 0 (h_0 = 0)
  for (int i = tid; i < 1024; i += 256) s_h[0][i] = 0ull;

  // seed gxr for t=0 (cold; paid once outside the steady-state loop)
  half8 gxr[4];
  {
    const _Float16* gb = g_gx + (size_t)rn_pt * GATES + gc0;
    #pragma unroll
    for (int off = 0; off < 4; ++off) {
      union { u64 u[2]; half8 h; } gg;
      gg.u[0] = *(const u64*)(gb + off * 128);
      gg.u[1] = *(const u64*)(gb + off * 128 + 16);
      gxr[off] = gg.h;
    }
  }
  __syncthreads();

  for (int t = 0; t < NT; ++t) {
    const int cur = t & 1, nxt = cur ^ 1;
    const bool hasnext = (t + 1 < NT);

    // 1) issue peer poll loads FIRST (nothing queues ahead of them)
    const u64* hsrc = g_hx + ((size_t)t * NCL + c) * 1024;
    u64 pv[8];
    #pragma unroll
    for (int kk = 0; kk < 4; ++kk) {
      pv[2 * kk]     = __hip_atomic_load(hsrc +       (peer0 + kk) * 64 + l,
                                         __ATOMIC_RELAXED, __HIP_MEMORY_SCOPE_AGENT);
      pv[2 * kk + 1] = __hip_atomic_load(hsrc + 512 + (peer0 + kk) * 64 + l,
                                         __ATOMIC_RELAXED, __HIP_MEMORY_SCOPE_AGENT);
    }

    floatx4 acc[8];
    #pragma unroll
    for (int i = 0; i < 8; ++i) acc[i] = (floatx4){0.f, 0.f, 0.f, 0.f};

    // 2) own-half MFMAs from LDS (SWAPPED: wf = A, h = B)
    #pragma unroll
    for (int kk = 0; kk < 4; ++kk) {
      union { u64 u[2]; half8 h; } af;
      af.u[0] = s_h[cur][kk * 64 + l];
      af.u[1] = s_h[cur][512 + kk * 64 + l];
      #pragma unroll
      for (int i = 0; i < 8; ++i)
        acc[i] = __builtin_amdgcn_mfma_f32_16x16x32_f16(wf[i][kk], af.h, acc[i], 0, 0, 0);
    }

    // 3) BATCHED spin: re-issue all pending chunks each iteration (~1 RTT)
    {
      bool pending = false;
      #pragma unroll
      for (int k = 0; k < 8; ++k) pending |= (pv[k] == SENT);
      int tries = 0;
      while (pending && ++tries < (1 << 18)) {
        pending = false;
        #pragma unroll
        for (int kk = 0; kk < 4; ++kk) {
          if (pv[2 * kk] == SENT)
            pv[2 * kk] = __hip_atomic_load(hsrc + (peer0 + kk) * 64 + l,
                                           __ATOMIC_RELAXED, __HIP_MEMORY_SCOPE_AGENT);
          if (pv[2 * kk + 1] == SENT)
            pv[2 * kk + 1] = __hip_atomic_load(hsrc + 512 + (peer0 + kk) * 64 + l,
                                               __ATOMIC_RELAXED, __HIP_MEMORY_SCOPE_AGENT);
        }
        #pragma unroll
        for (int k = 0; k < 8; ++k) pending |= (pv[k] == SENT);
      }
    }

    // 4) gx prefetch for t+1 (after spin exit; 8x 8B loads, delta cols)
    __builtin_amdgcn_sched_barrier(0);
    u64 gn[8];
    if (hasnext) {
      const _Float16* gb = g_gx + ((size_t)(t + 1) * NGRID + rn_pt) * GATES + gc0;
      #pragma unroll
      for (int off = 0; off < 4; ++off) {
        gn[2 * off]     = *(const u64*)(gb + off * 128);
        gn[2 * off + 1] = *(const u64*)(gb + off * 128 + 16);
      }
    }

    // 5) peer-half MFMAs (swapped)
    #pragma unroll
    for (int kk = 0; kk < 4; ++kk) {
      union { u64 u[2]; half8 h; } af;
      af.u[0] = pv[2 * kk];
      af.u[1] = pv[2 * kk + 1];
      #pragma unroll
      for (int i = 0; i < 8; ++i)
        acc[i] = __builtin_amdgcn_mfma_f32_16x16x32_f16(wf[i][4 + kk], af.h, acc[i], 0, 0, 0);
    }

    // 6) cell update: FULLY REGISTER-LOCAL. j = s*4+r; preact for gate off
    //    = acc[off*2 + s][r]; gxr[off][j] matches (delta-ordered load).
    {
      union { u64 u[2]; _Float16 h[8]; } pub;
      float yp = 0.f;
      #pragma unroll
      for (int j = 0; j < 8; ++j) {
        const int s = j >> 2, r = j & 3;
        const float gi = acc[0 + s][r] + (float)gxr[0][j];
        const float gf = acc[2 + s][r] + (float)gxr[1][j];
        const float gg = acc[4 + s][r] + (float)gxr[2][j];
        const float go = acc[6 + s][r] + (float)gxr[3][j];
        const float i_ = fsig(gi);
        const float f_ = fsig(gf);
        const float g_ = ftanh(gg);
        const float o_ = fsig(go);
        cs[j] = f_ * cs[j] + i_ * g_;
        const float h = o_ * ftanh(cs[j]);
        pub.h[j] = (_Float16)h;
        yp += wo[j] * h;
      }
      // 7) publish wave's ks slice (2 coalesced 512B stores) + own-half LDS
      if (hasnext) {
        u64* dst = g_hx + ((size_t)(t + 1) * NCL + c) * 1024 + (b * 4 + w) * 64 + l;
        __hip_atomic_store(dst,       pub.u[0], __ATOMIC_RELAXED, __HIP_MEMORY_SCOPE_AGENT);
        __hip_atomic_store(dst + 512, pub.u[1], __ATOMIC_RELAXED, __HIP_MEMORY_SCOPE_AGENT);
      }
      s_h[nxt][w * 64 + l]       = pub.u[0];
      s_h[nxt][512 + w * 64 + l] = pub.u[1];
      // 8) y: reduce partial over the 4 jg-lanes of this pt, then atomicAdd
      //    (jg-lane dim sets {jg*4+r, 16+jg*4+r} tile all 32 dims ✓)
      yp += __shfl_xor(yp, 16);
      yp += __shfl_xor(yp, 32);
      if (jg == 0 && n_pt < NGRID)
        atomicAdd(&y[(size_t)t * NGRID + n_pt], yp + bo_eff);
    }

    // 9) rotate gx prefetch into place
    if (hasnext) {
      #pragma unroll
      for (int off = 0; off < 4; ++off) {
        union { u64 u[2]; half8 h; } gg;
        gg.u[0] = gn[2 * off];
        gg.u[1] = gn[2 * off + 1];
        gxr[off] = gg.h;
      }
    }

    __syncthreads(); // single barrier: s_h(t+1) complete across waves
  }
}

extern "C" void kernel_launch(void* const* d_in, const int* in_sizes, int n_in,
                              void* d_out, int out_size, void* d_ws, size_t ws_size,
                              hipStream_t stream) {
  (void)in_sizes; (void)n_in; (void)out_size; (void)d_ws; (void)ws_size;
  const float* x     = (const float*)d_in[0];
  // d_in[1] = wt_ih (zeros in eval mode, unused)
  const float* W_in  = (const float*)d_in[2];
  const float* b_in  = (const float*)d_in[3];
  const float* W_ih  = (const float*)d_in[4];
  const float* W_hh  = (const float*)d_in[5];
  const float* b_ih  = (const float*)d_in[6];
  const float* b_hh  = (const float*)d_in[7];
  const float* W_out = (const float*)d_in[8];
  const float* b_out = (const float*)d_in[9];
  float* y           = (float*)d_out;

  hipLaunchKernelGGL(pack_wf_kernel, dim3(256), dim3(256), 0, stream, W_ih, W_hh);
  hipLaunchKernelGGL(gx_kernel, dim3(MBLK), dim3(256), 0, stream,
                     x, W_in, b_in, b_ih, b_hh, y);
  hipLaunchKernelGGL(rec_kernel, dim3(NCL * 2), dim3(256), 0, stream, W_out, b_out, y);
}